// Round 5
// baseline (123.278 us; speedup 1.0000x reference)
//
#include <hip/hip_runtime.h>

#define NQ  12
#define DIM 4096
#define TPB 256

typedef float v2f __attribute__((ext_vector_type(2)));
typedef float v4f __attribute__((ext_vector_type(4)));

// Inter-pass LDS layouts: per round-trip bit-permutation idx of the state
// index e, stored at padded slot s = idx + 2*(idx>>4) + 2*(idx>>7).
// For idx = E + 16B + 128F (E=low4 = consumer's 4 chunk bits, with the
// shared producer bit at idx bit0), s = E + 18B + 146F and the b128 quad is
// (E>>1 + B + F)&7 -- verified distinct across every 8-lane phase for all
// six (write,read) patterns below. All addresses are thread-base +
// compile-time immediate (no per-access VALU).

__device__ __forceinline__ float wave_reduce(float v) {
#pragma unroll
    for (int m = 32; m >= 1; m >>= 1) v += __shfl_xor(v, m, 64);
    return v;
}

// broadcast lane q's value to all lanes (lands in SGPR)
#define BCAST(v, q) __uint_as_float(__builtin_amdgcn_readlane(__float_as_uint(v), (q)))

// One circuit layer: unnormalized H on register-bit MC (1/sqrt2 folded into
// epilogue), then (X*RX if XGATE else RX) on bit MT where MC==1.
// ctv = (c,c), snv = (s,-s); off-diag = -i*s, so (-i*s)*z = snv * z.yx.
template <int MC, int MT, bool XGATE>
__device__ __forceinline__ void apply_layer(v2f* a, v2f ctv, v2f snv) {
#pragma unroll
    for (int i = 0; i < 16; ++i) {
        if (i & MC) continue;
        const int j = i | MC;
        const v2f t0 = a[i], t1 = a[j];
        a[i] = t0 + t1;          // v_pk_add_f32
        a[j] = t0 - t1;
    }
#pragma unroll
    for (int i = 0; i < 16; ++i) {
        if (!(i & MC) || (i & MT)) continue;   // control=1, target=0 slot
        const int j = i | MT;
        const v2f b0 = a[i], b1 = a[j];
        const v2f s0 = snv * b0.yx;            // v_pk_mul_f32
        const v2f s1 = snv * b1.yx;
        if (XGATE) {                           // X*RX = [[s, c],[c, s]]
            a[i] = ctv * b1 + s0;              // v_pk_fma_f32
            a[j] = ctv * b0 + s1;
        } else {                               // RX = [[c, s],[s, c]]
            a[i] = ctv * b0 + s1;
            a[j] = ctv * b1 + s0;
        }
    }
}

// pack/unpack helpers: b128 = two amps (reg k and k+8: the layout's bit0)
__device__ __forceinline__ void st_pair(v2f* p, v2f lo, v2f hi) {
    v4f w; w.x = lo.x; w.y = lo.y; w.z = hi.x; w.w = hi.y;
    *(v4f*)p = w;
}
__device__ __forceinline__ void ld_pair(const v2f* p, v2f* lo, v2f* hi) {
    const v4f v = *(const v4f*)p;
    v2f q0; q0.x = v.x; q0.y = v.y;
    v2f q1; q1.x = v.z; q1.y = v.w;
    *lo = q0; *hi = q1;
}

__global__ __launch_bounds__(TPB, 4) void qlayer_kernel(
        const float* __restrict__ state, const float* __restrict__ params,
        float* __restrict__ out) {
    __shared__ __align__(16) v2f amp[4668];   // 37344 B padded permuted buffer
    __shared__ float red[4];

    const int t = threadIdx.x;
    const int lane = t & 63;
    const long long sbase = (long long)blockIdx.x * DIM;

    // per-lane angle (lanes 0..11 hold cos/sin(theta_q/2)); broadcast via readlane
    const float th = params[lane < NQ ? lane : 0] * 0.5f;
    const float cl = cosf(th);
    const float sl = sinf(th);

    // ---- load 16 contiguous floats (64 B/thread) + norm reduction ----
    float x[16];
    const float4* gp = (const float4*)(state + sbase + t * 16);
    float ss = 0.f;
#pragma unroll
    for (int j = 0; j < 4; ++j) {
        const float4 v = gp[j];
        x[4 * j + 0] = v.x; x[4 * j + 1] = v.y;
        x[4 * j + 2] = v.z; x[4 * j + 3] = v.w;
        ss = fmaf(v.x, v.x, ss); ss = fmaf(v.y, v.y, ss);
        ss = fmaf(v.z, v.z, ss); ss = fmaf(v.w, v.w, ss);
    }
    ss = wave_reduce(ss);
    if (lane == 0) red[t >> 6] = ss;
    __syncthreads();
    const float nrm  = sqrtf(red[0] + red[1] + red[2] + red[3]);
    const float invd = 1.0f / (nrm + 1e-8f);

    // ---- encoding: re = clamp(v,-1,1); im = sign(v)*sqrt(1-re^2) ----
    // |q|^2 == 1 exactly => second normalization = 1/4096, folded into epilogue.
    v2f a[16];
#pragma unroll
    for (int k = 0; k < 16; ++k) {
        const float v   = x[k] * invd;
        const float re  = fminf(fmaxf(v, -1.0f), 1.0f);
        const float imb = sqrtf(fmaxf(1.0f - re * re, 0.f));
        const float im  = (v > 0.f) ? imb : ((v < 0.f) ? -imb : 0.f);
        v2f q; q.x = re; q.y = im;
        a[k] = q;
    }

#define CTV(q) ({ v2f _c; _c.x = BCAST(cl, q); _c.y = _c.x; _c; })
#define SNV(q) ({ float _s = BCAST(sl, q); v2f _v; _v.x = _s; _v.y = -_s; _v; })

    // ================= P1: regs = e{0..3}; thread: e{4..11} = t ==========
    apply_layer<1, 2, true>(a, CTV(0), SNV(0));   // L0: c=e0,t=e1 (+CNOT)
    apply_layer<2, 4, true>(a, CTV(1), SNV(1));   // L1
    apply_layer<4, 8, true>(a, CTV(2), SNV(2));   // L2
    // write layout A: idxA=[e3..e6][e0..e2][e7..e11]; pair bit0 = e3 = reg bit3
    {
        v2f* wp = &amp[2 * (t & 7) + 146 * (t >> 3)];
#pragma unroll
        for (int k = 0; k < 8; ++k) st_pair(&wp[18 * k], a[k], a[k + 8]);
    }
    __syncthreads();

    // ===== P2: regs = e{3..6}; thread: e{0,1,2} = t&7, e{7..11} = t>>3 ====
    {
        const v2f* rp = &amp[18 * (t & 7) + 146 * (t >> 3)];
#pragma unroll
        for (int m = 0; m < 8; ++m) ld_pair(&rp[2 * m], &a[2 * m], &a[2 * m + 1]);
    }
    apply_layer<1, 2, true>(a, CTV(3), SNV(3));   // L3: c=e3,t=e4
    apply_layer<2, 4, true>(a, CTV(4), SNV(4));   // L4
    apply_layer<4, 8, true>(a, CTV(5), SNV(5));   // L5
    __syncthreads();   // all layout-A reads done before layout-B writes
    // write layout B: idxB=[e6..e9][e3,e4,e5][e0,e1,e2][e10,e11]; bit0 = e6
    {
        v2f* wp = &amp[2 * ((t >> 3) & 7) + 146 * (t & 7) + 1168 * (t >> 6)];
#pragma unroll
        for (int k = 0; k < 8; ++k) st_pair(&wp[18 * k], a[k], a[k + 8]);
    }
    __syncthreads();

    // ===== P3: regs = e{6..9}; thread: e{3,4,5}=t&7, e{0,1,2}=(t>>3)&7,
    //           e{10,11}=t>>6 ===========================================
    {
        const v2f* rp = &amp[18 * (t & 7) + 146 * ((t >> 3) & 7) + 1168 * (t >> 6)];
#pragma unroll
        for (int m = 0; m < 8; ++m) ld_pair(&rp[2 * m], &a[2 * m], &a[2 * m + 1]);
    }
    apply_layer<1, 2, true>(a, CTV(6), SNV(6));   // L6: c=e6,t=e7
    apply_layer<2, 4, true>(a, CTV(7), SNV(7));   // L7
    apply_layer<4, 8, true>(a, CTV(8), SNV(8));   // L8
    __syncthreads();   // all layout-B reads done before layout-C writes
    // write layout C: idxC=[e9,e10,e11,e0][e6,e7,e8][e3,e4,e5][e1,e2]; bit0 = e9
    {
        v2f* wp = &amp[2 * (t >> 6) + 8 * ((t >> 3) & 1) + 146 * (t & 7)
                      + 1168 * ((t >> 4) & 3)];
#pragma unroll
        for (int k = 0; k < 8; ++k) st_pair(&wp[18 * k], a[k], a[k + 8]);
    }
    __syncthreads();

    // ===== P4: regs = e{9,10,11,0}; thread: e{3,4,5}=t&7, e{1,2}=(t>>3)&3,
    //           e{6,7,8}=t>>5 ============================================
    {
        const v2f* rp = &amp[18 * (t >> 5) + 146 * (t & 7) + 1168 * ((t >> 3) & 3)];
#pragma unroll
        for (int m = 0; m < 8; ++m) ld_pair(&rp[2 * m], &a[2 * m], &a[2 * m + 1]);
    }
    apply_layer<1, 2, true >(a, CTV(9),  SNV(9));   // L9:  c=e9,  t=e10
    apply_layer<2, 4, true >(a, CTV(10), SNV(10));  // L10: c=e10, t=e11
    apply_layer<4, 8, false>(a, CTV(11), SNV(11));  // L11: c=e11, t=e0 (RX only)

    // probs epilogue; scale = 1/4096 (encode norm) * (1/sqrt2)^24 = 2^-24
    // amp r at e = (r>>3) + 2*((t>>3)&3) + 8*(t&7) + 64*(t>>5) + 512*(r&7)
    // pair (e0=0, e0=1) = regs (k, k+8) -> one float2; wave covers a
    // contiguous 512B span per k (permuted within-wave order, coalesced).
    {
        const float scale = 0x1p-24f;
        float2* outp = (float2*)(out + sbase);
        const int obase = ((t >> 3) & 3) + 4 * (t & 7) + 32 * (t >> 5);
#pragma unroll
        for (int k = 0; k < 8; ++k) {
            const v2f q0 = a[k] * a[k];             // v_pk_mul_f32
            const v2f q1 = a[k | 8] * a[k | 8];
            outp[obase + (k << 8)] = make_float2((q0.x + q0.y) * scale,
                                                 (q1.x + q1.y) * scale);
        }
    }
#undef CTV
#undef SNV
}

extern "C" void kernel_launch(void* const* d_in, const int* in_sizes, int n_in,
                              void* d_out, int out_size, void* d_ws, size_t ws_size,
                              hipStream_t stream) {
    (void)in_sizes; (void)n_in; (void)out_size; (void)d_ws; (void)ws_size;
    const float* state  = (const float*)d_in[0];   // (8,512,4096) fp32
    const float* params = (const float*)d_in[1];   // (12,) fp32
    float* out = (float*)d_out;                    // (8,512,4096) fp32
    qlayer_kernel<<<dim3(4096), dim3(TPB), 0, stream>>>(state, params, out);
}